// Round 16
// baseline (253.093 us; speedup 1.0000x reference)
//
#include <hip/hip_runtime.h>
#include <hip/hip_bf16.h>

typedef __hip_bfloat16 bf16;

#define F 18
#define P 128
#define H 256
#define HEADS 8
#define HD 32
#define NCLS 625
#define FPH (F*P*H)        // 589824
#define RPS 589824         // per-scale buffer: 2304 rows x 256 (any permutation)
#define NT16 144           // 2304/16 row tiles per scale

// ---- fp32 workspace layout (float slots) ----
#define OF_DONE   8        // last-block ticket counter (uint)
#define OF_PTN    16
#define OF_RT     48
#define OF_W      80
#define OF_OSUM   128
#define OF_CTX    512
#define OF_FW     (OF_CTX + FPH)      // 590336
#define WO2_HALTW 0
#define WO2_HALTB 256
#define WO2_BQ    272
#define WO2_BK    1040
#define WO2_BV    1808
#define WO2_BO    2576
#define FW_TOTAL  3344
#define NF_TOTAL  (OF_FW + FW_TOTAL)  // 593680 floats ~= 2.4 MB

// ---- bf16 workspace layout (bf16 slots after fp32 area) ----
#define BB_WQT 0
#define BB_WKT 196608
#define BB_WVT 393216
#define BB_WOT 589824
#define BB_INP 786432                  // FPH
#define BB_QB  1376256                 // 3*RPS (swizzled frag layout)
#define BB_KB  (BB_QB + 3*RPS)
#define BB_VT  (BB_KB + 3*RPS)
#define BB_AO  (BB_VT + 3*RPS)         // summed attn out, A-frag swizzled

typedef __attribute__((ext_vector_type(8))) short s8v;
typedef __attribute__((ext_vector_type(4))) short s4v;
typedef __attribute__((ext_vector_type(4))) float f4v;

__device__ __forceinline__ float b2f(bf16 x){ return __bfloat162float(x); }
__device__ __forceinline__ unsigned short f2bu(float x){
    union { __hip_bfloat16 h; unsigned short u; } cv; cv.h = __float2bfloat16(x); return cv.u;
}
__device__ __forceinline__ float bu2f(unsigned short u){
    union { unsigned int x; float f; } cv; cv.x = ((unsigned int)u) << 16; return cv.f;
}
__device__ __forceinline__ void b2x2(unsigned int u, float& a, float& b){
    union { unsigned int x; float f; } c1, c2;
    c1.x = u << 16; c2.x = u & 0xffff0000u; a = c1.f; b = c2.f;
}

#if __has_builtin(__builtin_amdgcn_cvt_pk_bf16_f32)
typedef __attribute__((ext_vector_type(2))) __bf16 bf2_t;
__device__ __forceinline__ unsigned int pk2(float a, float b){
    union { bf2_t v; unsigned int u; } cv;
    cv.v = __builtin_amdgcn_cvt_pk_bf16_f32(a, b);
    return cv.u;
}
#else
__device__ __forceinline__ unsigned int pk2(float a, float b){
    return (unsigned int)f2bu(a) | ((unsigned int)f2bu(b) << 16);
}
#endif

#if __has_builtin(__builtin_amdgcn_exp2f)
__device__ __forceinline__ float fexp2(float x){ return __builtin_amdgcn_exp2f(x); }
#else
__device__ __forceinline__ float fexp2(float x){ return exp2f(x); }
#endif

__device__ __forceinline__ int imin(int a,int b){ return a<b?a:b; }
__device__ __forceinline__ int imax(int a,int b){ return a>b?a:b; }

__device__ __forceinline__ int detect_bf16_block(const unsigned int* __restrict__ embw,
                                                 int* scnt)
{
    if (threadIdx.x == 0) *scnt = 0;
    __syncthreads();
    int c = 0;
    {
        unsigned int e = (embw[2*threadIdx.x] >> 7) & 0xffu;
        if (e >= 120u && e <= 130u) c++;
        e = (embw[2*threadIdx.x + 1] >> 7) & 0xffu;
        if (e >= 120u && e <= 130u) c++;
    }
    atomicAdd(scnt, c);
    __syncthreads();
    return (*scnt > 256) ? 1 : 0;
}

// ---------------------------------------------------------------------------
// convert: mode 0 fp32 copy; mode 1 bf16 transposed weight; mode 2 embed.
// Also zeroes the fp32 state+context region (incl. the ticket counter).
// ---------------------------------------------------------------------------
struct ConvArgs {
    const void* src[11];
    int mode[11];
    int n[11];
    int off[11];
};
__global__ __launch_bounds__(256) void k_convert(ConvArgs a,
        const unsigned int* __restrict__ embw,
        float* __restrict__ ws, bf16* __restrict__ bb)
{
    __shared__ int scnt;
    const int isbf = detect_bf16_block(embw, &scnt);
    int gid = blockIdx.x*256 + threadIdx.x;
    if (gid < OF_FW) ws[gid] = 0.f;          // state + context + counter zero
#pragma unroll
    for (int t = 0; t < 11; ++t){
        if (gid < a.n[t]){
            float v = isbf ? b2f(((const bf16*)a.src[t])[gid])
                           : ((const float*)a.src[t])[gid];
            if (a.mode[t] == 0){
                ws[a.off[t] + gid] = v;
            } else if (a.mode[t] == 1){
                const int i = gid >> 16, rem = gid & 65535;
                const int k = rem >> 8, nn = rem & 255;
                bb[a.off[t] + (i << 16) + (nn << 8) + k] = __float2bfloat16(v);
            } else {
                bb[BB_INP + gid] = __float2bfloat16(v);
            }
            return;
        }
        gid -= a.n[t];
    }
}

// ---------------------------------------------------------------------------
// Fused QKV projection (+halting on the z==3 slice). Outputs in MFMA-frag-
// swizzled layouts. Q/K use swapped mfma operands (lane holds 4 consecutive
// output columns of one token -> 8B stores).
// ---------------------------------------------------------------------------
__global__ __launch_bounds__(256) void k_qkv_mfma(const bf16* __restrict__ X,
        const bf16* __restrict__ WQT, const bf16* __restrict__ WKT,
        const bf16* __restrict__ WVT, const float* __restrict__ fw,
        bf16* __restrict__ qball, bf16* __restrict__ kball, bf16* __restrict__ vball)
{
    const int tid = threadIdx.x;
    if (blockIdx.z == 3){
        if (blockIdx.x >= F || blockIdx.y != 0) return;
        __shared__ float hw[H];
        __shared__ float red[256];
        float* ws = (float*)fw - OF_FW;
        const float* hW = fw + WO2_HALTW;
        const int f = blockIdx.x;
        hw[tid] = hW[tid];
        __syncthreads();
        float sg = 0.f;
        if (tid < P){
            const uint4* row = (const uint4*)(X + (size_t)(f*P + tid)*H);
            float acc = fw[WO2_HALTB];
#pragma unroll
            for (int i = 0; i < 16; ++i){
                const uint4 u = row[i];
                float a0,a1,a2,a3,a4,a5,a6,a7;
                b2x2(u.x,a0,a1); b2x2(u.y,a2,a3); b2x2(u.z,a4,a5); b2x2(u.w,a6,a7);
                const int b = i*16;
                acc = fmaf(a0,hw[b+0],acc); acc = fmaf(a1,hw[b+1],acc);
                acc = fmaf(a2,hw[b+2],acc); acc = fmaf(a3,hw[b+3],acc);
                acc = fmaf(a4,hw[b+4],acc); acc = fmaf(a5,hw[b+5],acc);
                acc = fmaf(a6,hw[b+6],acc); acc = fmaf(a7,hw[b+7],acc);
            }
            sg = 1.f/(1.f + __expf(-acc));
        }
        red[tid] = sg;
        __syncthreads();
        for (int s = 128; s > 0; s >>= 1){ if (tid < s) red[tid] += red[tid+s]; __syncthreads(); }
        if (tid == 0){
            float pf = red[0] * (1.f/P);
            float pt = ws[OF_PTN + f], rt = ws[OF_RT + f];
            float run  = (pt < 1.f) ? 1.f : 0.f;
            float cond = (pt + pf*run > 0.99f) ? 1.f : 0.f;
            float nh   = cond*run;
            run = (1.f - cond)*run;
            pt += pf*run;
            rt += nh*(1.f - pt);
            pt += nh*rt;
            ws[OF_PTN + f] = pt; ws[OF_RT + f] = rt;
            ws[OF_W   + f] = pf*run + nh*rt;
        }
        return;
    }
    const int wave = tid >> 6, lane = tid & 63;
    const int lq = lane & 15, quad = lane >> 4;
    const int m0 = blockIdx.x * 64;
    const int n0 = blockIdx.y * 64 + wave * 16;
    const int i  = blockIdx.z;
    const int wo = i << 16;

    const bf16* arow[4];
#pragma unroll
    for (int mt = 0; mt < 4; ++mt)
        arow[mt] = X + (size_t)(m0 + mt*16 + lq)*H + quad*8;
    const bf16* bqp = WQT + wo + (size_t)(n0 + lq)*H + quad*8;
    const bf16* bkp = WKT + wo + (size_t)(n0 + lq)*H + quad*8;
    const bf16* bvp = WVT + wo + (size_t)(n0 + lq)*H + quad*8;

    f4v aq[4], ak[4], av[4];
#pragma unroll
    for (int mt = 0; mt < 4; ++mt){
        aq[mt] = (f4v){0.f,0.f,0.f,0.f};
        ak[mt] = (f4v){0.f,0.f,0.f,0.f};
        av[mt] = (f4v){0.f,0.f,0.f,0.f};
    }
#pragma unroll
    for (int k0 = 0; k0 < H; k0 += 32){
        const s8v bfq = *(const s8v*)(bqp + k0);
        const s8v bfk = *(const s8v*)(bkp + k0);
        const s8v bfv = *(const s8v*)(bvp + k0);
#pragma unroll
        for (int mt = 0; mt < 4; ++mt){
            const s8v af = *(const s8v*)(arow[mt] + k0);
            aq[mt] = __builtin_amdgcn_mfma_f32_16x16x32_bf16(bfq, af, aq[mt], 0, 0, 0);
            ak[mt] = __builtin_amdgcn_mfma_f32_16x16x32_bf16(bfk, af, ak[mt], 0, 0, 0);
            av[mt] = __builtin_amdgcn_mfma_f32_16x16x32_bf16(af, bfv, av[mt], 0, 0, 0);
        }
    }
    bf16* qo = qball + (size_t)i*RPS;
    bf16* ko = kball + (size_t)i*RPS;
    bf16* vo = vball + (size_t)i*RPS;

    const int cbase = n0 + 4*quad;
    const float4 bq4 = *(const float4*)(fw + WO2_BQ + i*256 + cbase);
    const float4 bk4 = *(const float4*)(fw + WO2_BK + i*256 + cbase);
    const int h2q  = cbase >> 5;
    const int dimq = (cbase >> 3) & 3;
    const int j2b  = cbase & 7;
    const int colv = n0 + lq;
    const float bvv = fw[WO2_BV + i*256 + colv];
    const int h2v = colv >> 5;
    const int half = (colv >> 4) & 1;
    const int lqv  = colv & 15;
#pragma unroll
    for (int mt = 0; mt < 4; ++mt){
        const int t16 = (m0 >> 4) + mt;
        const size_t qkidx = ((size_t)(h2q*NT16 + t16)*64 + lq + 16*dimq)*8 + j2b;
        uint2 qst, kst;
        qst.x = pk2(aq[mt][0] + bq4.x, aq[mt][1] + bq4.y);
        qst.y = pk2(aq[mt][2] + bq4.z, aq[mt][3] + bq4.w);
        kst.x = pk2(ak[mt][0] + bk4.x, ak[mt][1] + bk4.y);
        kst.y = pk2(ak[mt][2] + bk4.z, ak[mt][3] + bk4.w);
        *(uint2*)(qo + qkidx) = qst;
        *(uint2*)(ko + qkidx) = kst;
        const size_t vbase = ((size_t)(h2v*NT16 + t16)*64 + lqv + 16*quad)*8 + half*4;
        uint2 vst;
        vst.x = pk2(av[mt][0] + bvv, av[mt][1] + bvv);
        vst.y = pk2(av[mt][2] + bvv, av[mt][3] + bvv);
        *(uint2*)(vo + vbase) = vst;
    }
}

// ---------------------------------------------------------------------------
// Flash attention with exact chunk-partial merge in a COMMON BASE m.
// ---------------------------------------------------------------------------
#if __has_builtin(__builtin_amdgcn_mfma_f32_16x16x16bf16_1k)
#define ATTN_HAVE_1K 1
#else
#define ATTN_HAVE_1K 0
#endif

template<int SS>
__device__ __forceinline__ void attn_body(const bf16* __restrict__ qs,
        const bf16* __restrict__ ks, const bf16* __restrict__ vs,
        bf16* __restrict__ aos, int f, int h, int t, int lane)
{
    const int NW = F - SS + 1;
    const int lq = lane & 15, quad = lane >> 4;
    const int qt16 = f*8 + t;

    s8v qf;
    {
        const float SCL2 = 0.17677669529663687f * 1.4426950408889634f;
        union { s8v v; unsigned int u[4]; } qin, qsc;
        qin.v = *(const s8v*)(qs + ((size_t)(h*NT16 + qt16)*64 + lane)*8);
#pragma unroll
        for (int j = 0; j < 4; ++j){
            float a, b;
            b2x2(qin.u[j], a, b);
            qsc.u[j] = pk2(a*SCL2, b*SCL2);
        }
        qf = qsc.v;
    }

    const int wLo = imax(0, f - SS + 1);
    const int wHi = imin(NW - 1, f);
    const int cnt = wHi - wLo + 1;
    const int gHi = wHi + SS - 1;

    float m = -3e38f;
    float lw[SS];
    f4v ow0[SS], ow1[SS];
#pragma unroll
    for (int ws = 0; ws < SS; ++ws){
        lw[ws] = 0.f;
        ow0[ws] = (f4v){0.f,0.f,0.f,0.f};
        ow1[ws] = (f4v){0.f,0.f,0.f,0.f};
    }

    for (int g = wLo; g <= gHi; ++g){
        const int kt0 = g*8;
        f4v st[8];
#pragma unroll
        for (int tt = 0; tt < 4; ++tt){
            const s8v kf0 = *(const s8v*)(ks + ((size_t)(h*NT16 + kt0 + tt*2    )*64 + lane)*8);
            const s8v kf1 = *(const s8v*)(ks + ((size_t)(h*NT16 + kt0 + tt*2 + 1)*64 + lane)*8);
            f4v z = {0.f,0.f,0.f,0.f};
            st[2*tt]   = __builtin_amdgcn_mfma_f32_16x16x32_bf16(kf0, qf, z, 0, 0, 0);
            st[2*tt+1] = __builtin_amdgcn_mfma_f32_16x16x32_bf16(kf1, qf, z, 0, 0, 0);
        }
        union { uint4 q; s4v h2v[2]; } vA[4], vB[4];
#pragma unroll
        for (int tt = 0; tt < 4; ++tt){
            vA[tt].q = *(const uint4*)(vs + ((size_t)(h*NT16 + kt0 + tt*2    )*64 + lane)*8);
            vB[tt].q = *(const uint4*)(vs + ((size_t)(h*NT16 + kt0 + tt*2 + 1)*64 + lane)*8);
        }
        float mu = -3e38f;
#pragma unroll
        for (int t8 = 0; t8 < 8; ++t8)
            mu = fmaxf(mu, fmaxf(fmaxf(st[t8][0], st[t8][1]), fmaxf(st[t8][2], st[t8][3])));
        mu = fmaxf(mu, __shfl_xor(mu, 16));
        mu = fmaxf(mu, __shfl_xor(mu, 32));
        float Lg = 0.f;
#pragma unroll
        for (int t8 = 0; t8 < 8; ++t8){
#pragma unroll
            for (int r = 0; r < 4; ++r){
                const float e = fexp2(st[t8][r] - mu);
                st[t8][r] = e;
                Lg += e;
            }
        }
        Lg += __shfl_xor(Lg, 16);
        Lg += __shfl_xor(Lg, 32);
        f4v P0 = {0.f,0.f,0.f,0.f}, P1 = {0.f,0.f,0.f,0.f};
#pragma unroll
        for (int tt = 0; tt < 4; ++tt){
#if ATTN_HAVE_1K
            union { unsigned int u[2]; s4v v; } pf0, pf1;
            pf0.u[0] = pk2(st[2*tt][0],   st[2*tt][1]);
            pf0.u[1] = pk2(st[2*tt][2],   st[2*tt][3]);
            pf1.u[0] = pk2(st[2*tt+1][0], st[2*tt+1][1]);
            pf1.u[1] = pk2(st[2*tt+1][2], st[2*tt+1][3]);
            P0 = __builtin_amdgcn_mfma_f32_16x16x16bf16_1k(vA[tt].h2v[0], pf0.v, P0, 0, 0, 0);
            P0 = __builtin_amdgcn_mfma_f32_16x16x16bf16_1k(vB[tt].h2v[0], pf1.v, P0, 0, 0, 0);
            P1 = __builtin_amdgcn_mfma_f32_16x16x16bf16_1k(vA[tt].h2v[1], pf0.v, P1, 0, 0, 0);
            P1 = __builtin_amdgcn_mfma_f32_16x16x16bf16_1k(vB[tt].h2v[1], pf1.v, P1, 0, 0, 0);
#else
            union { s4v h2v[2]; s8v v; } va0, va1;
            va0.h2v[0] = vA[tt].h2v[0]; va0.h2v[1] = vB[tt].h2v[0];
            va1.h2v[0] = vA[tt].h2v[1]; va1.h2v[1] = vB[tt].h2v[1];
            const unsigned int p0x = pk2(st[2*tt][0],   st[2*tt][1]);
            const unsigned int p0y = pk2(st[2*tt][2],   st[2*tt][3]);
            const unsigned int p1x = pk2(st[2*tt+1][0], st[2*tt+1][1]);
            const unsigned int p1y = pk2(st[2*tt+1][2], st[2*tt+1][3]);
            const int srcA = lq + ((( quad<<1)      & 3) << 4);
            const int srcB = lq + ((((quad<<1) | 1) & 3) << 4);
            const unsigned int a0 = (unsigned int)__shfl((int)p0x, srcA);
            const unsigned int a1 = (unsigned int)__shfl((int)p0y, srcA);
            const unsigned int a2 = (unsigned int)__shfl((int)p0x, srcB);
            const unsigned int a3 = (unsigned int)__shfl((int)p0y, srcB);
            const unsigned int b0 = (unsigned int)__shfl((int)p1x, srcA);
            const unsigned int b1 = (unsigned int)__shfl((int)p1y, srcA);
            const unsigned int b2 = (unsigned int)__shfl((int)p1x, srcB);
            const unsigned int b3 = (unsigned int)__shfl((int)p1y, srcB);
            const bool hi = (quad >= 2);
            union { unsigned int u[4]; s8v v; } bfr;
            bfr.u[0] = hi ? b0 : a0; bfr.u[1] = hi ? b1 : a1;
            bfr.u[2] = hi ? b2 : a2; bfr.u[3] = hi ? b3 : a3;
            P0 = __builtin_amdgcn_mfma_f32_16x16x32_bf16(va0.v, bfr.v, P0, 0, 0, 0);
            P1 = __builtin_amdgcn_mfma_f32_16x16x32_bf16(va1.v, bfr.v, P1, 0, 0, 0);
#endif
        }
        float b;
        if (mu > m){
            const float al = fexp2(m - mu);
#pragma unroll
            for (int ws = 0; ws < SS; ++ws){
                lw[ws] *= al;
#pragma unroll
                for (int r = 0; r < 4; ++r){ ow0[ws][r] *= al; ow1[ws][r] *= al; }
            }
            m = mu;
            b = 1.f;
        } else {
            b = fexp2(mu - m);
        }
        const float Lgb = Lg * b;
#pragma unroll
        for (int ws = 0; ws < SS; ++ws){
            const int w = wLo + ws;
            if (w <= wHi && w <= g && w >= g - SS + 1){
                lw[ws] += Lgb;
#pragma unroll
                for (int r = 0; r < 4; ++r){
                    ow0[ws][r] = fmaf(P0[r], b, ow0[ws][r]);
                    ow1[ws][r] = fmaf(P1[r], b, ow1[ws][r]);
                }
            }
        }
    }
    f4v acc0 = {0.f,0.f,0.f,0.f}, acc1 = {0.f,0.f,0.f,0.f};
#pragma unroll
    for (int ws = 0; ws < SS; ++ws){
        if (ws < cnt){
            const float inv = 1.f / (lw[ws] * (float)cnt);
#pragma unroll
            for (int r = 0; r < 4; ++r){
                acc0[r] += ow0[ws][r]*inv;
                acc1[r] += ow1[ws][r]*inv;
            }
        }
    }
    const int grp0 = (4*h + (quad >> 1)) & 3;
    const int grp1 = (4*h + 2 + (quad >> 1)) & 3;
    const int off  = 4*(quad & 1);
    const size_t base = (size_t)(qt16*8 + h)*64;
    uint2 s0, s1;
    s0.x = pk2(acc0[0], acc0[1]); s0.y = pk2(acc0[2], acc0[3]);
    s1.x = pk2(acc1[0], acc1[1]); s1.y = pk2(acc1[2], acc1[3]);
    *(uint2*)(aos + (base + lq + 16*grp0)*8 + off) = s0;
    *(uint2*)(aos + (base + lq + 16*grp1)*8 + off) = s1;
}

__global__ __launch_bounds__(256) void k_attn_fused(const bf16* __restrict__ qball,
        const bf16* __restrict__ kball, const bf16* __restrict__ vball,
        bf16* __restrict__ aoall)
{
    const int bid = blockIdx.x;
    int i, rel;
    if (bid < 288)      { i = 2; rel = bid; }        // s=6 first (heavy)
    else if (bid < 576) { i = 1; rel = bid - 288; }
    else                { i = 0; rel = bid - 576; }
    const int f = rel >> 4;
    const int rest = rel & 15;
    const int h = rest >> 1;
    const int wave = threadIdx.x >> 6, lane = threadIdx.x & 63;
    const int t = (rest & 1)*4 + wave;

    const bf16* qs = qball + (size_t)i*RPS;
    const bf16* ks = kball + (size_t)i*RPS;
    const bf16* vs = vball + (size_t)i*RPS;
    bf16* aos = aoall + (size_t)i*RPS;

    if (i == 2)      attn_body<6>(qs, ks, vs, aos, f, h, t, lane);
    else if (i == 1) attn_body<4>(qs, ks, vs, aos, f, h, t, lane);
    else             attn_body<2>(qs, ks, vs, aos, f, h, t, lane);
}

// ---------------------------------------------------------------------------
// Output projection (32-row tiles, 288 blocks), 3 scales accumulated, fused
// with the transition epilogue. On the FINAL iteration: folds the context
// row-reduction into osum AND the LAST block (ticket pattern, no waiting)
// computes the classes output — removes both k_reduce and k_classes nodes.
// ---------------------------------------------------------------------------
__global__ __launch_bounds__(256) void k_oproj_trans(const bf16* __restrict__ aoall,
        const bf16* __restrict__ WOT, float* __restrict__ ws,
        bf16* __restrict__ inpb, float* __restrict__ context, int final,
        const unsigned int* __restrict__ embw,
        const void* __restrict__ clsW_raw, const void* __restrict__ clsb_raw,
        void* __restrict__ out)
{
    const int tid = threadIdx.x;
    const int wave = tid >> 6, lane = tid & 63;
    const int lq = lane & 15, quad = lane >> 4;
    const int m0 = blockIdx.x * 32;
    const int n0 = blockIdx.y * 64 + wave * 16;

    f4v acc[2];
    acc[0] = (f4v){0.f,0.f,0.f,0.f};
    acc[1] = (f4v){0.f,0.f,0.f,0.f};

    for (int i = 0; i < 3; ++i){
        const bf16* A = aoall + (size_t)i*RPS;
        const bf16* bp = WOT + (i<<16) + (size_t)(n0 + lq)*H + quad*8;
#pragma unroll
        for (int k0 = 0; k0 < H; k0 += 32){
            const s8v bf_ = *(const s8v*)(bp + k0);
#pragma unroll
            for (int mt = 0; mt < 2; ++mt){
                const s8v af = *(const s8v*)(A +
                    ((size_t)(((m0 >> 4) + mt)*8 + (k0 >> 5))*64 + lane)*8);
                acc[mt] = __builtin_amdgcn_mfma_f32_16x16x32_bf16(af, bf_, acc[mt], 0, 0, 0);
            }
        }
    }
    const int col = n0 + lq;
    const float bosum = ws[OF_FW + WO2_BO + col] + ws[OF_FW + WO2_BO + 256 + col]
                      + ws[OF_FW + WO2_BO + 512 + col];
    float psum = 0.f;
#pragma unroll
    for (int mt = 0; mt < 2; ++mt){
#pragma unroll
        for (int r = 0; r < 4; ++r){
            const int row = m0 + mt*16 + quad*4 + r;
            const float tval = 0.25f * (acc[mt][r] + bosum);
            const float wf = ws[OF_W + (row >> 7)];
            const size_t idx = (size_t)row*H + col;
            const float ctxv = tval*wf + context[idx]*(1.f - wf);
            inpb[idx] = __float2bfloat16(tval);
            context[idx] = ctxv;
            psum += ctxv;
        }
    }
    if (final){
        psum += __shfl_xor(psum, 16);
        psum += __shfl_xor(psum, 32);
        if (quad == 0) atomicAdd(&ws[OF_OSUM + col], psum);
        // ---- last-block-does-classes (ticket pattern; no block ever waits)
        __shared__ unsigned int lastflag;
        __syncthreads();                 // all waves' osum atomics issued
        __threadfence();                 // ... and visible device-wide
        if (tid == 0){
            unsigned int prev = atomicAdd((unsigned int*)ws + OF_DONE, 1u);
            lastflag = (prev == 287u) ? 1u : 0u;   // 72*4 = 288 blocks
        }
        __syncthreads();
        if (lastflag){
            __shared__ int scnt;
            __shared__ float os[H];
            const int isbf = detect_bf16_block(embw, &scnt);
            // coherent read of osum (atomic RMW returns the coherent value)
            os[tid] = atomicAdd(&ws[OF_OSUM + tid], 0.f);
            __syncthreads();
            for (int n = tid; n < NCLS; n += 256){
                float acc2 = isbf ? b2f(((const bf16*)clsb_raw)[n])
                                  : ((const float*)clsb_raw)[n];
                if (isbf){
                    const bf16* cw = (const bf16*)clsW_raw;
                    for (int hh = 0; hh < H; ++hh)
                        acc2 = fmaf(os[hh], b2f(cw[(size_t)hh*NCLS + n]), acc2);
                } else {
                    const float* cw = (const float*)clsW_raw;
                    for (int hh = 0; hh < H; ++hh)
                        acc2 = fmaf(os[hh], cw[(size_t)hh*NCLS + n], acc2);
                }
                if (isbf) ((bf16*)out)[n] = __float2bfloat16(acc2);
                else      ((float*)out)[n] = acc2;
            }
        }
    }
}

// ---------------------------------------------------------------------------
extern "C" void kernel_launch(void* const* d_in, const int* in_sizes, int n_in,
                              void* d_out, int out_size, void* d_ws, size_t ws_size,
                              hipStream_t stream)
{
    (void)in_sizes; (void)n_in; (void)out_size; (void)ws_size;
    float* WS = (float*)d_ws;
    float* context = WS + OF_CTX;
    float* fw      = WS + OF_FW;
    bf16*  bb      = (bf16*)(WS + NF_TOTAL);
    bf16*  inpb    = bb + BB_INP;
    bf16*  qb      = bb + BB_QB;
    bf16*  kb      = bb + BB_KB;
    bf16*  vT      = bb + BB_VT;
    bf16*  ao      = bb + BB_AO;

    ConvArgs ca;
    const int srcs[11]  = {0, 3, 4, 11, 13, 15, 17, 10, 12, 14, 16};
    const int modes[11] = {2, 0, 0, 0, 0, 0, 0, 1, 1, 1, 1};
    const int ns[11]    = {FPH, 256, 1, 768, 768, 768, 768,
                           196608, 196608, 196608, 196608};
    const int offs[11]  = {0,
        OF_FW+WO2_HALTW, OF_FW+WO2_HALTB,
        OF_FW+WO2_BQ, OF_FW+WO2_BK, OF_FW+WO2_BV, OF_FW+WO2_BO,
        BB_WQT, BB_WKT, BB_WVT, BB_WOT};
    int total = 0;
    for (int t = 0; t < 11; ++t){
        ca.src[t] = d_in[srcs[t]]; ca.mode[t] = modes[t];
        ca.n[t] = ns[t]; ca.off[t] = offs[t]; total += ns[t];
    }
    const int gmax = (total > OF_FW) ? total : OF_FW;
    k_convert<<<(gmax + 255)/256, 256, 0, stream>>>(ca,
        (const unsigned int*)d_in[0], WS, bb);

    for (int it = 0; it < 2; ++it){
        // z<3: QKV for scale z ; z==3 (x<18, y==0): halting/ACT update
        k_qkv_mfma<<<dim3(36, 4, 4), 256, 0, stream>>>(inpb,
            bb+BB_WQT, bb+BB_WKT, bb+BB_WVT, fw, qb, kb, vT);
        k_attn_fused<<<864, 256, 0, stream>>>(qb, kb, vT, ao);
        k_oproj_trans<<<dim3(72, 4), 256, 0, stream>>>(ao, bb+BB_WOT, WS,
            inpb, context, it == 1, (const unsigned int*)d_in[0],
            d_in[8], d_in[9], d_out);
    }
}

// Round 17
// 215.802 us; speedup vs baseline: 1.1728x; 1.1728x over previous
//
#include <hip/hip_runtime.h>
#include <hip/hip_bf16.h>

typedef __hip_bfloat16 bf16;

#define F 18
#define P 128
#define H 256
#define HEADS 8
#define HD 32
#define NCLS 625
#define FPH (F*P*H)        // 589824
#define RPS 589824         // per-scale buffer: 2304 rows x 256 (any permutation)
#define NT16 144           // 2304/16 row tiles per scale

// ---- fp32 workspace layout (float slots) ----
#define OF_PTN    16
#define OF_RT     48
#define OF_W      80
#define OF_OSUM   128
#define OF_CTX    512
#define OF_FW     (OF_CTX + FPH)      // 590336
#define WO2_HALTW 0
#define WO2_HALTB 256
#define WO2_BQ    272
#define WO2_BK    1040
#define WO2_BV    1808
#define WO2_BO    2576
#define FW_TOTAL  3344
#define NF_TOTAL  (OF_FW + FW_TOTAL)  // 593680 floats ~= 2.4 MB

// ---- bf16 workspace layout (bf16 slots after fp32 area) ----
#define BB_WQT 0
#define BB_WKT 196608
#define BB_WVT 393216
#define BB_WOT 589824
#define BB_INP 786432                  // FPH
#define BB_QB  1376256                 // 3*RPS (swizzled frag layout)
#define BB_KB  (BB_QB + 3*RPS)
#define BB_VT  (BB_KB + 3*RPS)
#define BB_AO  (BB_VT + 3*RPS)         // summed attn out, A-frag swizzled

typedef __attribute__((ext_vector_type(8))) short s8v;
typedef __attribute__((ext_vector_type(4))) short s4v;
typedef __attribute__((ext_vector_type(4))) float f4v;

__device__ __forceinline__ float b2f(bf16 x){ return __bfloat162float(x); }
__device__ __forceinline__ unsigned short f2bu(float x){
    union { __hip_bfloat16 h; unsigned short u; } cv; cv.h = __float2bfloat16(x); return cv.u;
}
__device__ __forceinline__ float bu2f(unsigned short u){
    union { unsigned int x; float f; } cv; cv.x = ((unsigned int)u) << 16; return cv.f;
}
__device__ __forceinline__ void b2x2(unsigned int u, float& a, float& b){
    union { unsigned int x; float f; } c1, c2;
    c1.x = u << 16; c2.x = u & 0xffff0000u; a = c1.f; b = c2.f;
}

#if __has_builtin(__builtin_amdgcn_cvt_pk_bf16_f32)
typedef __attribute__((ext_vector_type(2))) __bf16 bf2_t;
__device__ __forceinline__ unsigned int pk2(float a, float b){
    union { bf2_t v; unsigned int u; } cv;
    cv.v = __builtin_amdgcn_cvt_pk_bf16_f32(a, b);
    return cv.u;
}
#else
__device__ __forceinline__ unsigned int pk2(float a, float b){
    return (unsigned int)f2bu(a) | ((unsigned int)f2bu(b) << 16);
}
#endif

#if __has_builtin(__builtin_amdgcn_exp2f)
__device__ __forceinline__ float fexp2(float x){ return __builtin_amdgcn_exp2f(x); }
#else
__device__ __forceinline__ float fexp2(float x){ return exp2f(x); }
#endif

__device__ __forceinline__ int imin(int a,int b){ return a<b?a:b; }
__device__ __forceinline__ int imax(int a,int b){ return a>b?a:b; }

__device__ __forceinline__ int detect_bf16_block(const unsigned int* __restrict__ embw,
                                                 int* scnt)
{
    if (threadIdx.x == 0) *scnt = 0;
    __syncthreads();
    int c = 0;
    {
        unsigned int e = (embw[2*threadIdx.x] >> 7) & 0xffu;
        if (e >= 120u && e <= 130u) c++;
        e = (embw[2*threadIdx.x + 1] >> 7) & 0xffu;
        if (e >= 120u && e <= 130u) c++;
    }
    atomicAdd(scnt, c);
    __syncthreads();
    return (*scnt > 256) ? 1 : 0;
}

// ---------------------------------------------------------------------------
// convert: mode 0 fp32 copy; mode 1 bf16 transposed weight; mode 2 embed.
// Also zeroes the fp32 state+context region (replaces the memset node).
// ---------------------------------------------------------------------------
struct ConvArgs {
    const void* src[11];
    int mode[11];
    int n[11];
    int off[11];
};
__global__ __launch_bounds__(256) void k_convert(ConvArgs a,
        const unsigned int* __restrict__ embw,
        float* __restrict__ ws, bf16* __restrict__ bb)
{
    __shared__ int scnt;
    const int isbf = detect_bf16_block(embw, &scnt);
    int gid = blockIdx.x*256 + threadIdx.x;
    if (gid < OF_FW) ws[gid] = 0.f;          // state + context zero-init
#pragma unroll
    for (int t = 0; t < 11; ++t){
        if (gid < a.n[t]){
            float v = isbf ? b2f(((const bf16*)a.src[t])[gid])
                           : ((const float*)a.src[t])[gid];
            if (a.mode[t] == 0){
                ws[a.off[t] + gid] = v;
            } else if (a.mode[t] == 1){
                const int i = gid >> 16, rem = gid & 65535;
                const int k = rem >> 8, nn = rem & 255;
                bb[a.off[t] + (i << 16) + (nn << 8) + k] = __float2bfloat16(v);
            } else {
                bb[BB_INP + gid] = __float2bfloat16(v);
            }
            return;
        }
        gid -= a.n[t];
    }
}

// ---------------------------------------------------------------------------
// Fused QKV projection (+halting on the z==3 slice). Outputs in MFMA-frag-
// swizzled layouts. Q/K use swapped mfma operands (lane holds 4 consecutive
// output columns of one token -> 8B stores).
// ---------------------------------------------------------------------------
__global__ __launch_bounds__(256) void k_qkv_mfma(const bf16* __restrict__ X,
        const bf16* __restrict__ WQT, const bf16* __restrict__ WKT,
        const bf16* __restrict__ WVT, const float* __restrict__ fw,
        bf16* __restrict__ qball, bf16* __restrict__ kball, bf16* __restrict__ vball)
{
    const int tid = threadIdx.x;
    if (blockIdx.z == 3){
        if (blockIdx.x >= F || blockIdx.y != 0) return;
        __shared__ float hw[H];
        __shared__ float red[256];
        float* ws = (float*)fw - OF_FW;
        const float* hW = fw + WO2_HALTW;
        const int f = blockIdx.x;
        hw[tid] = hW[tid];
        __syncthreads();
        float sg = 0.f;
        if (tid < P){
            const uint4* row = (const uint4*)(X + (size_t)(f*P + tid)*H);
            float acc = fw[WO2_HALTB];
#pragma unroll
            for (int i = 0; i < 16; ++i){
                const uint4 u = row[i];
                float a0,a1,a2,a3,a4,a5,a6,a7;
                b2x2(u.x,a0,a1); b2x2(u.y,a2,a3); b2x2(u.z,a4,a5); b2x2(u.w,a6,a7);
                const int b = i*16;
                acc = fmaf(a0,hw[b+0],acc); acc = fmaf(a1,hw[b+1],acc);
                acc = fmaf(a2,hw[b+2],acc); acc = fmaf(a3,hw[b+3],acc);
                acc = fmaf(a4,hw[b+4],acc); acc = fmaf(a5,hw[b+5],acc);
                acc = fmaf(a6,hw[b+6],acc); acc = fmaf(a7,hw[b+7],acc);
            }
            sg = 1.f/(1.f + __expf(-acc));
        }
        red[tid] = sg;
        __syncthreads();
        for (int s = 128; s > 0; s >>= 1){ if (tid < s) red[tid] += red[tid+s]; __syncthreads(); }
        if (tid == 0){
            float pf = red[0] * (1.f/P);
            float pt = ws[OF_PTN + f], rt = ws[OF_RT + f];
            float run  = (pt < 1.f) ? 1.f : 0.f;
            float cond = (pt + pf*run > 0.99f) ? 1.f : 0.f;
            float nh   = cond*run;
            run = (1.f - cond)*run;
            pt += pf*run;
            rt += nh*(1.f - pt);
            pt += nh*rt;
            ws[OF_PTN + f] = pt; ws[OF_RT + f] = rt;
            ws[OF_W   + f] = pf*run + nh*rt;
        }
        return;
    }
    const int wave = tid >> 6, lane = tid & 63;
    const int lq = lane & 15, quad = lane >> 4;
    const int m0 = blockIdx.x * 64;
    const int n0 = blockIdx.y * 64 + wave * 16;
    const int i  = blockIdx.z;
    const int wo = i << 16;

    const bf16* arow[4];
#pragma unroll
    for (int mt = 0; mt < 4; ++mt)
        arow[mt] = X + (size_t)(m0 + mt*16 + lq)*H + quad*8;
    const bf16* bqp = WQT + wo + (size_t)(n0 + lq)*H + quad*8;
    const bf16* bkp = WKT + wo + (size_t)(n0 + lq)*H + quad*8;
    const bf16* bvp = WVT + wo + (size_t)(n0 + lq)*H + quad*8;

    f4v aq[4], ak[4], av[4];
#pragma unroll
    for (int mt = 0; mt < 4; ++mt){
        aq[mt] = (f4v){0.f,0.f,0.f,0.f};
        ak[mt] = (f4v){0.f,0.f,0.f,0.f};
        av[mt] = (f4v){0.f,0.f,0.f,0.f};
    }
#pragma unroll
    for (int k0 = 0; k0 < H; k0 += 32){
        const s8v bfq = *(const s8v*)(bqp + k0);
        const s8v bfk = *(const s8v*)(bkp + k0);
        const s8v bfv = *(const s8v*)(bvp + k0);
#pragma unroll
        for (int mt = 0; mt < 4; ++mt){
            const s8v af = *(const s8v*)(arow[mt] + k0);
            aq[mt] = __builtin_amdgcn_mfma_f32_16x16x32_bf16(bfq, af, aq[mt], 0, 0, 0);
            ak[mt] = __builtin_amdgcn_mfma_f32_16x16x32_bf16(bfk, af, ak[mt], 0, 0, 0);
            av[mt] = __builtin_amdgcn_mfma_f32_16x16x32_bf16(af, bfv, av[mt], 0, 0, 0);
        }
    }
    bf16* qo = qball + (size_t)i*RPS;
    bf16* ko = kball + (size_t)i*RPS;
    bf16* vo = vball + (size_t)i*RPS;

    const int cbase = n0 + 4*quad;
    const float4 bq4 = *(const float4*)(fw + WO2_BQ + i*256 + cbase);
    const float4 bk4 = *(const float4*)(fw + WO2_BK + i*256 + cbase);
    const int h2q  = cbase >> 5;
    const int dimq = (cbase >> 3) & 3;
    const int j2b  = cbase & 7;
    const int colv = n0 + lq;
    const float bvv = fw[WO2_BV + i*256 + colv];
    const int h2v = colv >> 5;
    const int half = (colv >> 4) & 1;
    const int lqv  = colv & 15;
#pragma unroll
    for (int mt = 0; mt < 4; ++mt){
        const int t16 = (m0 >> 4) + mt;
        const size_t qkidx = ((size_t)(h2q*NT16 + t16)*64 + lq + 16*dimq)*8 + j2b;
        uint2 qst, kst;
        qst.x = pk2(aq[mt][0] + bq4.x, aq[mt][1] + bq4.y);
        qst.y = pk2(aq[mt][2] + bq4.z, aq[mt][3] + bq4.w);
        kst.x = pk2(ak[mt][0] + bk4.x, ak[mt][1] + bk4.y);
        kst.y = pk2(ak[mt][2] + bk4.z, ak[mt][3] + bk4.w);
        *(uint2*)(qo + qkidx) = qst;
        *(uint2*)(ko + qkidx) = kst;
        const size_t vbase = ((size_t)(h2v*NT16 + t16)*64 + lqv + 16*quad)*8 + half*4;
        uint2 vst;
        vst.x = pk2(av[mt][0] + bvv, av[mt][1] + bvv);
        vst.y = pk2(av[mt][2] + bvv, av[mt][3] + bvv);
        *(uint2*)(vo + vbase) = vst;
    }
}

// ---------------------------------------------------------------------------
// Flash attention with exact chunk-partial merge in a COMMON BASE m.
// ---------------------------------------------------------------------------
#if __has_builtin(__builtin_amdgcn_mfma_f32_16x16x16bf16_1k)
#define ATTN_HAVE_1K 1
#else
#define ATTN_HAVE_1K 0
#endif

template<int SS>
__device__ __forceinline__ void attn_body(const bf16* __restrict__ qs,
        const bf16* __restrict__ ks, const bf16* __restrict__ vs,
        bf16* __restrict__ aos, int f, int h, int t, int lane)
{
    const int NW = F - SS + 1;
    const int lq = lane & 15, quad = lane >> 4;
    const int qt16 = f*8 + t;

    s8v qf;
    {
        const float SCL2 = 0.17677669529663687f * 1.4426950408889634f;
        union { s8v v; unsigned int u[4]; } qin, qsc;
        qin.v = *(const s8v*)(qs + ((size_t)(h*NT16 + qt16)*64 + lane)*8);
#pragma unroll
        for (int j = 0; j < 4; ++j){
            float a, b;
            b2x2(qin.u[j], a, b);
            qsc.u[j] = pk2(a*SCL2, b*SCL2);
        }
        qf = qsc.v;
    }

    const int wLo = imax(0, f - SS + 1);
    const int wHi = imin(NW - 1, f);
    const int cnt = wHi - wLo + 1;
    const int gHi = wHi + SS - 1;

    float m = -3e38f;
    float lw[SS];
    f4v ow0[SS], ow1[SS];
#pragma unroll
    for (int ws = 0; ws < SS; ++ws){
        lw[ws] = 0.f;
        ow0[ws] = (f4v){0.f,0.f,0.f,0.f};
        ow1[ws] = (f4v){0.f,0.f,0.f,0.f};
    }

    for (int g = wLo; g <= gHi; ++g){
        const int kt0 = g*8;
        f4v st[8];
#pragma unroll
        for (int tt = 0; tt < 4; ++tt){
            const s8v kf0 = *(const s8v*)(ks + ((size_t)(h*NT16 + kt0 + tt*2    )*64 + lane)*8);
            const s8v kf1 = *(const s8v*)(ks + ((size_t)(h*NT16 + kt0 + tt*2 + 1)*64 + lane)*8);
            f4v z = {0.f,0.f,0.f,0.f};
            st[2*tt]   = __builtin_amdgcn_mfma_f32_16x16x32_bf16(kf0, qf, z, 0, 0, 0);
            st[2*tt+1] = __builtin_amdgcn_mfma_f32_16x16x32_bf16(kf1, qf, z, 0, 0, 0);
        }
        union { uint4 q; s4v h2v[2]; } vA[4], vB[4];
#pragma unroll
        for (int tt = 0; tt < 4; ++tt){
            vA[tt].q = *(const uint4*)(vs + ((size_t)(h*NT16 + kt0 + tt*2    )*64 + lane)*8);
            vB[tt].q = *(const uint4*)(vs + ((size_t)(h*NT16 + kt0 + tt*2 + 1)*64 + lane)*8);
        }
        float mu = -3e38f;
#pragma unroll
        for (int t8 = 0; t8 < 8; ++t8)
            mu = fmaxf(mu, fmaxf(fmaxf(st[t8][0], st[t8][1]), fmaxf(st[t8][2], st[t8][3])));
        mu = fmaxf(mu, __shfl_xor(mu, 16));
        mu = fmaxf(mu, __shfl_xor(mu, 32));
        float Lg = 0.f;
#pragma unroll
        for (int t8 = 0; t8 < 8; ++t8){
#pragma unroll
            for (int r = 0; r < 4; ++r){
                const float e = fexp2(st[t8][r] - mu);
                st[t8][r] = e;
                Lg += e;
            }
        }
        Lg += __shfl_xor(Lg, 16);
        Lg += __shfl_xor(Lg, 32);
        f4v P0 = {0.f,0.f,0.f,0.f}, P1 = {0.f,0.f,0.f,0.f};
#pragma unroll
        for (int tt = 0; tt < 4; ++tt){
#if ATTN_HAVE_1K
            union { unsigned int u[2]; s4v v; } pf0, pf1;
            pf0.u[0] = pk2(st[2*tt][0],   st[2*tt][1]);
            pf0.u[1] = pk2(st[2*tt][2],   st[2*tt][3]);
            pf1.u[0] = pk2(st[2*tt+1][0], st[2*tt+1][1]);
            pf1.u[1] = pk2(st[2*tt+1][2], st[2*tt+1][3]);
            P0 = __builtin_amdgcn_mfma_f32_16x16x16bf16_1k(vA[tt].h2v[0], pf0.v, P0, 0, 0, 0);
            P0 = __builtin_amdgcn_mfma_f32_16x16x16bf16_1k(vB[tt].h2v[0], pf1.v, P0, 0, 0, 0);
            P1 = __builtin_amdgcn_mfma_f32_16x16x16bf16_1k(vA[tt].h2v[1], pf0.v, P1, 0, 0, 0);
            P1 = __builtin_amdgcn_mfma_f32_16x16x16bf16_1k(vB[tt].h2v[1], pf1.v, P1, 0, 0, 0);
#else
            union { s4v h2v[2]; s8v v; } va0, va1;
            va0.h2v[0] = vA[tt].h2v[0]; va0.h2v[1] = vB[tt].h2v[0];
            va1.h2v[0] = vA[tt].h2v[1]; va1.h2v[1] = vB[tt].h2v[1];
            const unsigned int p0x = pk2(st[2*tt][0],   st[2*tt][1]);
            const unsigned int p0y = pk2(st[2*tt][2],   st[2*tt][3]);
            const unsigned int p1x = pk2(st[2*tt+1][0], st[2*tt+1][1]);
            const unsigned int p1y = pk2(st[2*tt+1][2], st[2*tt+1][3]);
            const int srcA = lq + ((( quad<<1)      & 3) << 4);
            const int srcB = lq + ((((quad<<1) | 1) & 3) << 4);
            const unsigned int a0 = (unsigned int)__shfl((int)p0x, srcA);
            const unsigned int a1 = (unsigned int)__shfl((int)p0y, srcA);
            const unsigned int a2 = (unsigned int)__shfl((int)p0x, srcB);
            const unsigned int a3 = (unsigned int)__shfl((int)p0y, srcB);
            const unsigned int b0 = (unsigned int)__shfl((int)p1x, srcA);
            const unsigned int b1 = (unsigned int)__shfl((int)p1y, srcA);
            const unsigned int b2 = (unsigned int)__shfl((int)p1x, srcB);
            const unsigned int b3 = (unsigned int)__shfl((int)p1y, srcB);
            const bool hi = (quad >= 2);
            union { unsigned int u[4]; s8v v; } bfr;
            bfr.u[0] = hi ? b0 : a0; bfr.u[1] = hi ? b1 : a1;
            bfr.u[2] = hi ? b2 : a2; bfr.u[3] = hi ? b3 : a3;
            P0 = __builtin_amdgcn_mfma_f32_16x16x32_bf16(va0.v, bfr.v, P0, 0, 0, 0);
            P1 = __builtin_amdgcn_mfma_f32_16x16x32_bf16(va1.v, bfr.v, P1, 0, 0, 0);
#endif
        }
        float b;
        if (mu > m){
            const float al = fexp2(m - mu);
#pragma unroll
            for (int ws = 0; ws < SS; ++ws){
                lw[ws] *= al;
#pragma unroll
                for (int r = 0; r < 4; ++r){ ow0[ws][r] *= al; ow1[ws][r] *= al; }
            }
            m = mu;
            b = 1.f;
        } else {
            b = fexp2(mu - m);
        }
        const float Lgb = Lg * b;
#pragma unroll
        for (int ws = 0; ws < SS; ++ws){
            const int w = wLo + ws;
            if (w <= wHi && w <= g && w >= g - SS + 1){
                lw[ws] += Lgb;
#pragma unroll
                for (int r = 0; r < 4; ++r){
                    ow0[ws][r] = fmaf(P0[r], b, ow0[ws][r]);
                    ow1[ws][r] = fmaf(P1[r], b, ow1[ws][r]);
                }
            }
        }
    }
    f4v acc0 = {0.f,0.f,0.f,0.f}, acc1 = {0.f,0.f,0.f,0.f};
#pragma unroll
    for (int ws = 0; ws < SS; ++ws){
        if (ws < cnt){
            const float inv = 1.f / (lw[ws] * (float)cnt);
#pragma unroll
            for (int r = 0; r < 4; ++r){
                acc0[r] += ow0[ws][r]*inv;
                acc1[r] += ow1[ws][r]*inv;
            }
        }
    }
    const int grp0 = (4*h + (quad >> 1)) & 3;
    const int grp1 = (4*h + 2 + (quad >> 1)) & 3;
    const int off  = 4*(quad & 1);
    const size_t base = (size_t)(qt16*8 + h)*64;
    uint2 s0, s1;
    s0.x = pk2(acc0[0], acc0[1]); s0.y = pk2(acc0[2], acc0[3]);
    s1.x = pk2(acc1[0], acc1[1]); s1.y = pk2(acc1[2], acc1[3]);
    *(uint2*)(aos + (base + lq + 16*grp0)*8 + off) = s0;
    *(uint2*)(aos + (base + lq + 16*grp1)*8 + off) = s1;
}

__global__ __launch_bounds__(256) void k_attn_fused(const bf16* __restrict__ qball,
        const bf16* __restrict__ kball, const bf16* __restrict__ vball,
        bf16* __restrict__ aoall)
{
    const int bid = blockIdx.x;
    int i, rel;
    if (bid < 288)      { i = 2; rel = bid; }        // s=6 first (heavy)
    else if (bid < 576) { i = 1; rel = bid - 288; }
    else                { i = 0; rel = bid - 576; }
    const int f = rel >> 4;
    const int rest = rel & 15;
    const int h = rest >> 1;
    const int wave = threadIdx.x >> 6, lane = threadIdx.x & 63;
    const int t = (rest & 1)*4 + wave;

    const bf16* qs = qball + (size_t)i*RPS;
    const bf16* ks = kball + (size_t)i*RPS;
    const bf16* vs = vball + (size_t)i*RPS;
    bf16* aos = aoall + (size_t)i*RPS;

    if (i == 2)      attn_body<6>(qs, ks, vs, aos, f, h, t, lane);
    else if (i == 1) attn_body<4>(qs, ks, vs, aos, f, h, t, lane);
    else             attn_body<2>(qs, ks, vs, aos, f, h, t, lane);
}

// ---------------------------------------------------------------------------
// Output projection (32-row tiles, 288 blocks), 3 scales accumulated, fused
// with the transition epilogue. Final iteration folds the context reduction
// into osum (per-lane partial + cross-quad shfl + one atomic per col/block).
// ---------------------------------------------------------------------------
__global__ __launch_bounds__(256) void k_oproj_trans(const bf16* __restrict__ aoall,
        const bf16* __restrict__ WOT, float* __restrict__ ws,
        bf16* __restrict__ inpb, float* __restrict__ context, int final)
{
    const int tid = threadIdx.x;
    const int wave = tid >> 6, lane = tid & 63;
    const int lq = lane & 15, quad = lane >> 4;
    const int m0 = blockIdx.x * 32;
    const int n0 = blockIdx.y * 64 + wave * 16;

    f4v acc[2];
    acc[0] = (f4v){0.f,0.f,0.f,0.f};
    acc[1] = (f4v){0.f,0.f,0.f,0.f};

    for (int i = 0; i < 3; ++i){
        const bf16* A = aoall + (size_t)i*RPS;
        const bf16* bp = WOT + (i<<16) + (size_t)(n0 + lq)*H + quad*8;
#pragma unroll
        for (int k0 = 0; k0 < H; k0 += 32){
            const s8v bf_ = *(const s8v*)(bp + k0);
#pragma unroll
            for (int mt = 0; mt < 2; ++mt){
                const s8v af = *(const s8v*)(A +
                    ((size_t)(((m0 >> 4) + mt)*8 + (k0 >> 5))*64 + lane)*8);
                acc[mt] = __builtin_amdgcn_mfma_f32_16x16x32_bf16(af, bf_, acc[mt], 0, 0, 0);
            }
        }
    }
    const int col = n0 + lq;
    const float bosum = ws[OF_FW + WO2_BO + col] + ws[OF_FW + WO2_BO + 256 + col]
                      + ws[OF_FW + WO2_BO + 512 + col];
    float psum = 0.f;
#pragma unroll
    for (int mt = 0; mt < 2; ++mt){
#pragma unroll
        for (int r = 0; r < 4; ++r){
            const int row = m0 + mt*16 + quad*4 + r;
            const float tval = 0.25f * (acc[mt][r] + bosum);
            const float wf = ws[OF_W + (row >> 7)];
            const size_t idx = (size_t)row*H + col;
            const float ctxv = tval*wf + context[idx]*(1.f - wf);
            inpb[idx] = __float2bfloat16(tval);
            context[idx] = ctxv;
            psum += ctxv;
        }
    }
    if (final){
        psum += __shfl_xor(psum, 16);
        psum += __shfl_xor(psum, 32);
        if (quad == 0) atomicAdd(&ws[OF_OSUM + col], psum);
    }
}

// ---------------------------------------------------------------------------
// classes = osum @ cls_W + cls_b. Latency-bound GEMV fixed with 8 partial
// accumulators + unroll-by-8 (keeps >=8 loads in flight, breaks the
// load->fma dependent chain that made the serial version ~20 us).
// ---------------------------------------------------------------------------
__global__ __launch_bounds__(256) void k_classes(const float* __restrict__ ws,
        const unsigned int* __restrict__ embw,
        const void* __restrict__ clsW_raw, const void* __restrict__ clsb_raw,
        void* __restrict__ out)
{
    __shared__ int scnt;
    __shared__ float os[H];
    const int isbf = detect_bf16_block(embw, &scnt);
    const int tid = threadIdx.x;
    os[tid] = ws[OF_OSUM + tid];
    __syncthreads();
    const int n = blockIdx.x*256 + tid;
    if (n < NCLS){
        float a0=0.f,a1=0.f,a2=0.f,a3=0.f,a4=0.f,a5=0.f,a6=0.f,a7=0.f;
        if (isbf){
            const bf16* cw = (const bf16*)clsW_raw;
#pragma unroll
            for (int hh = 0; hh < H; hh += 8){
                const size_t b = (size_t)hh*NCLS + n;
                a0 = fmaf(os[hh+0], b2f(cw[b          ]), a0);
                a1 = fmaf(os[hh+1], b2f(cw[b +   NCLS ]), a1);
                a2 = fmaf(os[hh+2], b2f(cw[b + 2*NCLS ]), a2);
                a3 = fmaf(os[hh+3], b2f(cw[b + 3*NCLS ]), a3);
                a4 = fmaf(os[hh+4], b2f(cw[b + 4*NCLS ]), a4);
                a5 = fmaf(os[hh+5], b2f(cw[b + 5*NCLS ]), a5);
                a6 = fmaf(os[hh+6], b2f(cw[b + 6*NCLS ]), a6);
                a7 = fmaf(os[hh+7], b2f(cw[b + 7*NCLS ]), a7);
            }
        } else {
            const float* cw = (const float*)clsW_raw;
#pragma unroll
            for (int hh = 0; hh < H; hh += 8){
                const size_t b = (size_t)hh*NCLS + n;
                a0 = fmaf(os[hh+0], cw[b          ], a0);
                a1 = fmaf(os[hh+1], cw[b +   NCLS ], a1);
                a2 = fmaf(os[hh+2], cw[b + 2*NCLS ], a2);
                a3 = fmaf(os[hh+3], cw[b + 3*NCLS ], a3);
                a4 = fmaf(os[hh+4], cw[b + 4*NCLS ], a4);
                a5 = fmaf(os[hh+5], cw[b + 5*NCLS ], a5);
                a6 = fmaf(os[hh+6], cw[b + 6*NCLS ], a6);
                a7 = fmaf(os[hh+7], cw[b + 7*NCLS ], a7);
            }
        }
        float bias = isbf ? b2f(((const bf16*)clsb_raw)[n])
                          : ((const float*)clsb_raw)[n];
        const float acc = (((a0+a1)+(a2+a3)) + ((a4+a5)+(a6+a7))) + bias;
        if (isbf) ((bf16*)out)[n] = __float2bfloat16(acc);
        else      ((float*)out)[n] = acc;
    }
}

// ---------------------------------------------------------------------------
extern "C" void kernel_launch(void* const* d_in, const int* in_sizes, int n_in,
                              void* d_out, int out_size, void* d_ws, size_t ws_size,
                              hipStream_t stream)
{
    (void)in_sizes; (void)n_in; (void)out_size; (void)ws_size;
    float* WS = (float*)d_ws;
    float* context = WS + OF_CTX;
    float* fw      = WS + OF_FW;
    bf16*  bb      = (bf16*)(WS + NF_TOTAL);
    bf16*  inpb    = bb + BB_INP;
    bf16*  qb      = bb + BB_QB;
    bf16*  kb      = bb + BB_KB;
    bf16*  vT      = bb + BB_VT;
    bf16*  ao      = bb + BB_AO;

    ConvArgs ca;
    const int srcs[11]  = {0, 3, 4, 11, 13, 15, 17, 10, 12, 14, 16};
    const int modes[11] = {2, 0, 0, 0, 0, 0, 0, 1, 1, 1, 1};
    const int ns[11]    = {FPH, 256, 1, 768, 768, 768, 768,
                           196608, 196608, 196608, 196608};
    const int offs[11]  = {0,
        OF_FW+WO2_HALTW, OF_FW+WO2_HALTB,
        OF_FW+WO2_BQ, OF_FW+WO2_BK, OF_FW+WO2_BV, OF_FW+WO2_BO,
        BB_WQT, BB_WKT, BB_WVT, BB_WOT};
    int total = 0;
    for (int t = 0; t < 11; ++t){
        ca.src[t] = d_in[srcs[t]]; ca.mode[t] = modes[t];
        ca.n[t] = ns[t]; ca.off[t] = offs[t]; total += ns[t];
    }
    const int gmax = (total > OF_FW) ? total : OF_FW;
    k_convert<<<(gmax + 255)/256, 256, 0, stream>>>(ca,
        (const unsigned int*)d_in[0], WS, bb);

    for (int it = 0; it < 2; ++it){
        // z<3: QKV for scale z ; z==3 (x<18, y==0): halting/ACT update
        k_qkv_mfma<<<dim3(36, 4, 4), 256, 0, stream>>>(inpb,
            bb+BB_WQT, bb+BB_WKT, bb+BB_WVT, fw, qb, kb, vT);
        k_attn_fused<<<864, 256, 0, stream>>>(qb, kb, vT, ao);
        k_oproj_trans<<<dim3(72, 4), 256, 0, stream>>>(ao, bb+BB_WOT, WS,
            inpb, context, it == 1);
    }
    k_classes<<<3, 256, 0, stream>>>(WS, (const unsigned int*)d_in[0],
        d_in[8], d_in[9], d_out);
}